// Round 16
// baseline (150.997 us; speedup 1.0000x reference)
//
#include <hip/hip_runtime.h>

namespace {
constexpr int DEPTH    = 11;
constexpr int IN_W     = 768;
constexpr int LEAF_W   = 16;
constexpr int OUT_W    = 768;
constexpr int N_NODES  = (1 << DEPTH) - 1;   // 2047
constexpr int N_LEAVES = (1 << DEPTH);       // 2048
constexpr int BATCH    = 8192;
constexpr int G        = 4;                  // same-leaf samples per wave
constexpr int MAX_TASKS = (BATCH + (G - 1) * N_LEAVES) / G;  // 3584
}

// ---------------- Kernel A: tree routing (one wave per sample) ----------------
// COALESCED: lane L reads float-chunk 4L of each 3 KB row (16 lines/instr).
// fp64 accumulation keeps decision error far below the fp32 reference's own
// rounding -> routing decisions match.
__global__ __launch_bounds__(256) void fff_route(
    const float* __restrict__ x,
    const float* __restrict__ nw,
    const float* __restrict__ nb,
    int* __restrict__ leaf_of,
    int* __restrict__ rank_of,
    int* __restrict__ cnt)
{
    const int lane = threadIdx.x & 63;
    const int s    = (int)((blockIdx.x * blockDim.x + threadIdx.x) >> 6);

    const float* xp = x + (size_t)s * IN_W + 4 * lane;
    const float4 xv0 = *(const float4*)(xp + 0);
    const float4 xv1 = *(const float4*)(xp + 256);
    const float4 xv2 = *(const float4*)(xp + 512);

    int node = 0;
    #pragma unroll 1
    for (int d = 0; d < DEPTH; ++d) {
        const float* wp = nw + (size_t)node * IN_W + 4 * lane;
        const float4 a0 = *(const float4*)(wp + 0);
        const float4 a1 = *(const float4*)(wp + 256);
        const float4 a2 = *(const float4*)(wp + 512);
        double acc = 0.0;
        acc = fma((double)a0.x, (double)xv0.x, acc);
        acc = fma((double)a0.y, (double)xv0.y, acc);
        acc = fma((double)a0.z, (double)xv0.z, acc);
        acc = fma((double)a0.w, (double)xv0.w, acc);
        acc = fma((double)a1.x, (double)xv1.x, acc);
        acc = fma((double)a1.y, (double)xv1.y, acc);
        acc = fma((double)a1.z, (double)xv1.z, acc);
        acc = fma((double)a1.w, (double)xv1.w, acc);
        acc = fma((double)a2.x, (double)xv2.x, acc);
        acc = fma((double)a2.y, (double)xv2.y, acc);
        acc = fma((double)a2.z, (double)xv2.z, acc);
        acc = fma((double)a2.w, (double)xv2.w, acc);
        #pragma unroll
        for (int off = 32; off > 0; off >>= 1)
            acc += __shfl_xor(acc, off, 64);
        const double score = acc + (double)nb[node];
        node = 2 * node + 1 + (score >= 0.0 ? 1 : 0);
    }
    const int leaf = node - N_NODES;

    if (lane == 0) {
        leaf_of[s] = leaf;
        rank_of[s] = atomicAdd(&cnt[leaf], 1);
    }
}

// ------- Kernel B: dual exclusive scan (sample offsets + group offsets) -------
__global__ void fff_scan(const int* __restrict__ cnt,
                         int* __restrict__ off,
                         int* __restrict__ goff,
                         int* __restrict__ ntasks)
{
    const int lane = threadIdx.x & 63;        // launched with 64 threads
    const int base = lane * (N_LEAVES / 64);  // 32 leaves per lane
    int c[N_LEAVES / 64], gl[N_LEAVES / 64];
    int s1 = 0, s2 = 0;
    #pragma unroll
    for (int i = 0; i < N_LEAVES / 64; ++i) {
        c[i] = cnt[base + i]; s1 += c[i];
        gl[i] = (c[i] + G - 1) / G; s2 += gl[i];
    }
    int v1 = s1, v2 = s2;
    #pragma unroll
    for (int d = 1; d < 64; d <<= 1) {
        int u1 = __shfl_up(v1, d, 64);
        int u2 = __shfl_up(v2, d, 64);
        if (lane >= d) { v1 += u1; v2 += u2; }
    }
    int r1 = v1 - s1, r2 = v2 - s2;
    #pragma unroll
    for (int i = 0; i < N_LEAVES / 64; ++i) {
        off[base + i]  = r1; r1 += c[i];
        goff[base + i] = r2; r2 += gl[i];
    }
    if (lane == 63) *ntasks = v2;
}

// ---------------- Kernel C: scatter samples into leaf-sorted order ----------------
__global__ __launch_bounds__(256) void fff_scatter(
    const int* __restrict__ leaf_of, const int* __restrict__ rank_of,
    const int* __restrict__ off, int* __restrict__ sorted)
{
    const int s = blockIdx.x * blockDim.x + threadIdx.x;
    if (s < BATCH) sorted[off[leaf_of[s]] + rank_of[s]] = s;
}

// ------- Kernel C2: emit per-group tasks {start, n, leaf} (one thread/leaf) -------
__global__ __launch_bounds__(256) void fff_tasks(
    const int* __restrict__ cnt, const int* __restrict__ off,
    const int* __restrict__ goff, int4* __restrict__ tasks)
{
    const int l = blockIdx.x * blockDim.x + threadIdx.x;
    if (l < N_LEAVES) {
        int n = cnt[l], o = off[l];
        int g0 = goff[l];
        for (int j = 0; n > 0; ++j, n -= G, o += G)
            tasks[g0 + j] = make_int4(o, n < G ? n : G, l, 0);
    }
}

// scheduling fence: pins burst boundaries; waitcnts stay compiler-owned.
#define SB() __builtin_amdgcn_sched_barrier(0)

// ---- Kernel D: one wave per task, ALL-COALESCED, live-set < 128 VGPR ----
// Layer 2 iterates column-chunk-major (m = 256-col chunk): oa shrinks from 48
// to 16 regs, stores flush per chunk, and the double-buffer chains across
// chunk boundaries so the load pipeline never drains. Peak live ~80 regs --
// the R13-R15 spill (VGPR clamp at 128) cannot recur.
__global__ __launch_bounds__(256, 3) void fff_mlp_co2(
    const float* __restrict__ x,
    const float* __restrict__ w1,
    const float* __restrict__ b1,
    const float* __restrict__ w2,
    const int* __restrict__ sorted,
    const int4* __restrict__ tasks,
    const int* __restrict__ ntasks_p,
    float* __restrict__ out)
{
    __shared__ float xbuf[4][G * IN_W];   // 48 KB; wave-private slices, no barriers

    const int lane = threadIdx.x & 63;
    const int wv   = (int)(threadIdx.x >> 6);
    const int rq   = lane >> 2;          // row-in-group 0..15
    // XCD-bijective swizzle: 896 blocks = 8 XCDs x 112 contiguous vblocks
    const int vb = (int)((blockIdx.x & 7) * (gridDim.x >> 3) + (blockIdx.x >> 3));
    const int t  = vb * 4 + wv;
    const int nt = *ntasks_p;
    if (t >= nt) return;

    const int4 task = tasks[t];
    const int start = __builtin_amdgcn_readfirstlane(task.x);
    const int n     = __builtin_amdgcn_readfirstlane(task.y);
    const int leaf  = __builtin_amdgcn_readfirstlane(task.z);

    int sidx[G];
    #pragma unroll
    for (int g = 0; g < G; ++g)
        sidx[g] = __builtin_amdgcn_readfirstlane(sorted[start + (g < n ? g : n - 1)]);

    const float* w1g = w1 + (size_t)leaf * (IN_W * LEAF_W);   // uniform (SGPR base)
    const float* w2g = w2 + (size_t)leaf * (LEAF_W * OUT_W);
    const float* b1g = b1 + (size_t)leaf * LEAF_W;

    // ---- stage x into this wave's LDS slice (coalesced loads, b128 writes) ----
    float* xw = &xbuf[wv][0];
    #pragma unroll
    for (int g = 0; g < G; ++g) {
        const float* xp = x + (size_t)sidx[g] * IN_W + 4 * lane;
        const float4 a = *(const float4*)(xp + 0);
        const float4 b = *(const float4*)(xp + 256);
        const float4 c = *(const float4*)(xp + 512);
        *(float4*)(xw + g * IN_W + 4 * lane + 0)   = a;
        *(float4*)(xw + g * IN_W + 4 * lane + 256) = b;
        *(float4*)(xw + g * IN_W + 4 * lane + 512) = c;
    }
    SB();

    float4 hacc[G];
    #pragma unroll
    for (int g = 0; g < G; ++g) hacc[g] = make_float4(0.f, 0.f, 0.f, 0.f);

    float4 WA[4], WB[4];

#define L1_LOADB(k0, B) do { \
    _Pragma("unroll") \
    for (int j = 0; j < 4; ++j) \
        B[j] = *(const float4*)(w1g + ((k0) + j) * 256 + 4 * lane); \
    } while (0)
#define L1_FMAB(k0, B) do { \
    _Pragma("unroll") \
    for (int j = 0; j < 4; ++j) { \
        const int row = 16 * ((k0) + j) + rq; \
        _Pragma("unroll") \
        for (int g = 0; g < G; ++g) { \
            const float xv = xw[g * IN_W + row]; \
            hacc[g].x = fmaf(xv, B[j].x, hacc[g].x); \
            hacc[g].y = fmaf(xv, B[j].y, hacc[g].y); \
            hacc[g].z = fmaf(xv, B[j].z, hacc[g].z); \
            hacc[g].w = fmaf(xv, B[j].w, hacc[g].w); \
        } \
    } } while (0)

    // ---- layer 1: 48 coalesced loads as 12 double-buffered bursts of 4 ----
    L1_LOADB(0, WA); SB();
    L1_LOADB(4, WB); SB();
    L1_FMAB(0,  WA); SB(); L1_LOADB(8,  WA); SB();
    L1_FMAB(4,  WB); SB(); L1_LOADB(12, WB); SB();
    L1_FMAB(8,  WA); SB(); L1_LOADB(16, WA); SB();
    L1_FMAB(12, WB); SB(); L1_LOADB(20, WB); SB();
    L1_FMAB(16, WA); SB(); L1_LOADB(24, WA); SB();
    L1_FMAB(20, WB); SB(); L1_LOADB(28, WB); SB();
    L1_FMAB(24, WA); SB(); L1_LOADB(32, WA); SB();
    L1_FMAB(28, WB); SB(); L1_LOADB(36, WB); SB();
    L1_FMAB(32, WA); SB(); L1_LOADB(40, WA); SB();
    L1_FMAB(36, WB); SB(); L1_LOADB(44, WB); SB();
    L1_FMAB(40, WA); SB();
    L1_FMAB(44, WB); SB();

    float4 VA[4], VB[4];
    // L2 burst: rows l0..l0+3, column chunk m (256 floats): 1 KB-span loads
#define L2_LOADB(m, l0, B) do { \
    _Pragma("unroll") \
    for (int j = 0; j < 4; ++j) \
        B[j] = *(const float4*)(w2g + ((l0) + j) * OUT_W + (m) * 256 + 4 * lane); \
    } while (0)

    // prefetch chunk-0 rows 0..7; latency hides under the reduce
    L2_LOADB(0, 0, VA); SB();
    L2_LOADB(0, 4, VB); SB();

    // ---- reduce h across the 16 lanes of each column class ----
    float hr[4][G];   // hr[c][g]: this lane's h cols 4*(lane&3)+c
    #pragma unroll
    for (int g = 0; g < G; ++g) {
        float4 v = hacc[g];
        #pragma unroll
        for (int o2 = 4; o2 < 64; o2 <<= 1) {
            v.x += __shfl_xor(v.x, o2, 64);
            v.y += __shfl_xor(v.y, o2, 64);
            v.z += __shfl_xor(v.z, o2, 64);
            v.w += __shfl_xor(v.w, o2, 64);
        }
        hr[0][g] = v.x; hr[1][g] = v.y; hr[2][g] = v.z; hr[3][g] = v.w;
    }
    {   // bias + relu: lane's class c = lane&3 owns cols 4c..4c+3
        const float4 bv = *(const float4*)(b1g + 4 * (lane & 3));
        #pragma unroll
        for (int g = 0; g < G; ++g) {
            hr[0][g] = fmaxf(hr[0][g] + bv.x, 0.f);
            hr[1][g] = fmaxf(hr[1][g] + bv.y, 0.f);
            hr[2][g] = fmaxf(hr[2][g] + bv.z, 0.f);
            hr[3][g] = fmaxf(hr[3][g] + bv.w, 0.f);
        }
    }

    float4 oa[G];   // 16 regs only -- one column chunk at a time

#define OA_ZERO() do { \
    _Pragma("unroll") \
    for (int g = 0; g < G; ++g) oa[g] = make_float4(0.f, 0.f, 0.f, 0.f); \
    } while (0)
    // h[l] lives in lanes with lane&3 == l>>2, element l&3 -> const-lane shfl
#define L2_FMAB(l0, B) do { \
    _Pragma("unroll") \
    for (int j = 0; j < 4; ++j) { \
        const int l = (l0) + j; \
        _Pragma("unroll") \
        for (int g = 0; g < G; ++g) { \
            const float hb = __shfl(hr[l & 3][g], l >> 2, 64); \
            oa[g].x = fmaf(hb, B[j].x, oa[g].x); \
            oa[g].y = fmaf(hb, B[j].y, oa[g].y); \
            oa[g].z = fmaf(hb, B[j].z, oa[g].z); \
            oa[g].w = fmaf(hb, B[j].w, oa[g].w); \
        } \
    } } while (0)
#define OA_STORE(m) do { \
    _Pragma("unroll") \
    for (int g = 0; g < G; ++g) if (g < n) \
        *(float4*)(out + (size_t)sidx[g] * OUT_W + (m) * 256 + 4 * lane) = oa[g]; \
    } while (0)

    // ---- layer 2: 3 column chunks x 16 rows; dbuf chains across chunks ----
    OA_ZERO();
    L2_FMAB(0,  VA); SB(); L2_LOADB(0, 8,  VA); SB();
    L2_FMAB(4,  VB); SB(); L2_LOADB(0, 12, VB); SB();
    L2_FMAB(8,  VA); SB(); L2_LOADB(1, 0,  VA); SB();
    L2_FMAB(12, VB); SB(); L2_LOADB(1, 4,  VB); SB();
    OA_STORE(0);

    OA_ZERO();
    L2_FMAB(0,  VA); SB(); L2_LOADB(1, 8,  VA); SB();
    L2_FMAB(4,  VB); SB(); L2_LOADB(1, 12, VB); SB();
    L2_FMAB(8,  VA); SB(); L2_LOADB(2, 0,  VA); SB();
    L2_FMAB(12, VB); SB(); L2_LOADB(2, 4,  VB); SB();
    OA_STORE(1);

    OA_ZERO();
    L2_FMAB(0,  VA); SB(); L2_LOADB(2, 8,  VA); SB();
    L2_FMAB(4,  VB); SB(); L2_LOADB(2, 12, VB); SB();
    L2_FMAB(8,  VA); SB();
    L2_FMAB(12, VB); SB();
    OA_STORE(2);

#undef L1_LOADB
#undef L1_FMAB
#undef L2_LOADB
#undef L2_FMAB
#undef OA_ZERO
#undef OA_STORE
}

extern "C" void kernel_launch(void* const* d_in, const int* in_sizes, int n_in,
                              void* d_out, int out_size, void* d_ws, size_t ws_size,
                              hipStream_t stream) {
    const float* x  = (const float*)d_in[0];
    const float* nw = (const float*)d_in[1];
    const float* nb = (const float*)d_in[2];
    const float* w1 = (const float*)d_in[3];
    const float* b1 = (const float*)d_in[4];
    const float* w2 = (const float*)d_in[5];
    float* o        = (float*)d_out;

    // ws (ints): cnt[2048] off[2048] goff[2048] ntasks[8] leaf[8192] rank[8192]
    //            sorted[8192] | tasks int4[3584]
    int* cnt    = (int*)d_ws;
    int* off    = cnt + N_LEAVES;
    int* goff   = off + N_LEAVES;
    int* ntasks = goff + N_LEAVES;
    int* leaf   = ntasks + 8;
    int* rank   = leaf + BATCH;
    int* sorted = rank + BATCH;
    int4* tasks = (int4*)(sorted + BATCH);

    (void)hipMemsetAsync(cnt, 0, N_LEAVES * sizeof(int), stream);

    fff_route  <<<dim3(BATCH / 4),    dim3(256), 0, stream>>>(x, nw, nb, leaf, rank, cnt);
    fff_scan   <<<dim3(1),            dim3(64),  0, stream>>>(cnt, off, goff, ntasks);
    fff_scatter<<<dim3(BATCH/256),    dim3(256), 0, stream>>>(leaf, rank, off, sorted);
    fff_tasks  <<<dim3(N_LEAVES/256), dim3(256), 0, stream>>>(cnt, off, goff, tasks);
    fff_mlp_co2<<<dim3(MAX_TASKS/4),  dim3(256), 0, stream>>>(
        x, w1, b1, w2, sorted, tasks, ntasks, o);
}